// Round 1
// baseline (4744.427 us; speedup 1.0000x reference)
//
#include <hip/hip_runtime.h>
#include <hip/hip_bf16.h>

#define NN 100000
#define NE 800000
#define NG 2048
#define DIN 74
#define DH 256
#define DM1 1024
#define DM2 512

// ---------------- degrees & norms ----------------
__global__ void k_deg(const int* __restrict__ src, const int* __restrict__ dst,
                      int* __restrict__ outd, int* __restrict__ ind) {
  int e = blockIdx.x * blockDim.x + threadIdx.x;
  if (e < NE) {
    atomicAdd(&outd[src[e]], 1);
    atomicAdd(&ind[dst[e]], 1);
  }
}

__global__ void k_norm(const int* __restrict__ outd, const int* __restrict__ ind,
                       float* __restrict__ onorm, float* __restrict__ inorm) {
  int i = blockIdx.x * blockDim.x + threadIdx.x;
  if (i < NN) {
    onorm[i] = rsqrtf(fmaxf((float)outd[i], 1.f));
    inorm[i] = rsqrtf(fmaxf((float)ind[i], 1.f));
  }
}

// ---------------- CSR build (scan + counting sort) ----------------
__global__ void k_scan_block(const int* __restrict__ deg, int* __restrict__ incl,
                             int* __restrict__ bsum, int n) {
  __shared__ int s[1024];
  int t = threadIdx.x;
  int i = blockIdx.x * 1024 + t;
  int v = (i < n) ? deg[i] : 0;
  s[t] = v;
  __syncthreads();
  for (int off = 1; off < 1024; off <<= 1) {
    int x = (t >= off) ? s[t - off] : 0;
    __syncthreads();
    s[t] += x;
    __syncthreads();
  }
  if (i < n) incl[i] = s[t];
  if (t == 1023) bsum[blockIdx.x] = s[1023];
}

__global__ void k_scan_sums(int* bsum, int nb) {
  if (threadIdx.x == 0 && blockIdx.x == 0) {
    int run = 0;
    for (int b = 0; b < nb; ++b) { int v = bsum[b]; bsum[b] = run; run += v; }
  }
}

__global__ void k_scan_add(const int* __restrict__ incl, const int* __restrict__ bsum,
                           const int* __restrict__ deg,
                           int* __restrict__ offs, int* __restrict__ cursor, int n) {
  int i = blockIdx.x * blockDim.x + threadIdx.x;
  if (i < n) {
    int v = incl[i] + bsum[i >> 10];
    offs[i + 1] = v;
    cursor[i] = v - deg[i];
    if (i == 0) offs[0] = 0;
  }
}

__global__ void k_scatter(const int* __restrict__ src, const int* __restrict__ dst,
                          int* __restrict__ cursor, int* __restrict__ ssrc) {
  int e = blockIdx.x * blockDim.x + threadIdx.x;
  if (e < NE) {
    int pos = atomicAdd(&cursor[dst[e]], 1);
    ssrc[pos] = src[e];
  }
}

// ---------------- SpMM (gather by dst row, wave per row) ----------------
__global__ void k_spmm74(const float* __restrict__ h, const int* __restrict__ offs,
                         const int* __restrict__ ssrc, const float* __restrict__ onorm,
                         const float* __restrict__ inorm, float* __restrict__ m) {
  int row = blockIdx.x * 4 + (threadIdx.x >> 6);
  if (row >= NN) return;
  int lane = threadIdx.x & 63;
  int beg = offs[row], end = offs[row + 1];
  float a0 = 0.f, a1 = 0.f;
  for (int e = beg; e < end; ++e) {
    int s = ssrc[e];
    float w = onorm[s];
    const float* hr = h + (size_t)s * DIN;
    a0 += w * hr[lane];
    if (lane < DIN - 64) a1 += w * hr[64 + lane];
  }
  float win = inorm[row];
  float* mr = m + (size_t)row * DIN;
  mr[lane] = a0 * win;
  if (lane < DIN - 64) mr[64 + lane] = a1 * win;
}

__global__ void k_spmm256(const float* __restrict__ x, const int* __restrict__ offs,
                          const int* __restrict__ ssrc, const float* __restrict__ onorm,
                          const float* __restrict__ inorm, float* __restrict__ m) {
  int row = blockIdx.x * 4 + (threadIdx.x >> 6);
  if (row >= NN) return;
  int lane = threadIdx.x & 63;
  int beg = offs[row], end = offs[row + 1];
  float4 acc = make_float4(0.f, 0.f, 0.f, 0.f);
  for (int e = beg; e < end; ++e) {
    int s = ssrc[e];
    float w = onorm[s];
    float4 v = *(const float4*)(x + (size_t)s * DH + lane * 4);
    acc.x += w * v.x; acc.y += w * v.y; acc.z += w * v.z; acc.w += w * v.w;
  }
  float win = inorm[row];
  float4 o = make_float4(acc.x * win, acc.y * win, acc.z * win, acc.w * win);
  *(float4*)(m + (size_t)row * DH + lane * 4) = o;
}

// ---------------- fp32 tiled GEMM, fused bias + activation ----------------
// ACT: 0=none, 1=relu, 2=leaky_relu(0.01)
template <int ACT>
__global__ __launch_bounds__(256) void k_gemm(const float* __restrict__ A,
                                              const float* __restrict__ B,
                                              const float* __restrict__ bias,
                                              float* __restrict__ C,
                                              int M, int K, int Nc) {
  __shared__ float As[16][68];  // [k][m], pad 68 -> only free 2-way conflicts
  __shared__ float Bs[16][68];  // [k][n]
  int tid = threadIdx.x;
  int tx = tid & 15, ty = tid >> 4;
  int r0 = blockIdx.x * 64;
  int c0 = blockIdx.y * 64;
  float acc[4][4] = {};
  for (int k0 = 0; k0 < K; k0 += 16) {
#pragma unroll
    for (int idx = tid; idx < 1024; idx += 256) {
      int mm = idx >> 4, kk = idx & 15;
      int gr = r0 + mm, gk = k0 + kk;
      As[kk][mm] = (gr < M && gk < K) ? A[(size_t)gr * K + gk] : 0.f;
    }
#pragma unroll
    for (int idx = tid; idx < 1024; idx += 256) {
      int kk = idx >> 6, nn = idx & 63;
      int gk = k0 + kk, gc = c0 + nn;
      Bs[kk][nn] = (gk < K && gc < Nc) ? B[(size_t)gk * Nc + gc] : 0.f;
    }
    __syncthreads();
#pragma unroll
    for (int kk = 0; kk < 16; ++kk) {
      float4 a = *(const float4*)&As[kk][ty * 4];
      float4 b = *(const float4*)&Bs[kk][tx * 4];
      float av[4] = {a.x, a.y, a.z, a.w};
      float bv[4] = {b.x, b.y, b.z, b.w};
#pragma unroll
      for (int i = 0; i < 4; ++i)
#pragma unroll
        for (int j = 0; j < 4; ++j) acc[i][j] += av[i] * bv[j];
    }
    __syncthreads();
  }
#pragma unroll
  for (int i = 0; i < 4; ++i) {
    int gr = r0 + ty * 4 + i;
    if (gr >= M) continue;
#pragma unroll
    for (int j = 0; j < 4; ++j) {
      int gc = c0 + tx * 4 + j;
      if (gc >= Nc) continue;
      float v = acc[i][j] + bias[gc];
      if (ACT == 1) v = fmaxf(v, 0.f);
      if (ACT == 2) v = (v > 0.f) ? v : 0.01f * v;
      C[(size_t)gr * Nc + gc] = v;
    }
  }
}

// ---------------- pooling + MLP tail ----------------
__global__ void k_gbounds(const int* __restrict__ gid, int* __restrict__ gstart) {
  int g = blockIdx.x * blockDim.x + threadIdx.x;
  if (g > NG) return;
  int lo = 0, hi = NN;
  while (lo < hi) {
    int mid = (lo + hi) >> 1;
    if (gid[mid] < g) lo = mid + 1; else hi = mid;
  }
  gstart[g] = lo;
}

__global__ void k_pool(const float* __restrict__ x, const int* __restrict__ gstart,
                       float* __restrict__ pooled) {
  int g = blockIdx.x * 4 + (threadIdx.x >> 6);
  if (g >= NG) return;
  int lane = threadIdx.x & 63;
  int beg = gstart[g], end = gstart[g + 1];
  float4 acc = make_float4(0.f, 0.f, 0.f, 0.f);
  for (int r = beg; r < end; ++r) {
    float4 v = *(const float4*)(x + (size_t)r * DH + lane * 4);
    acc.x += v.x; acc.y += v.y; acc.z += v.z; acc.w += v.w;
  }
  float cnt = fmaxf((float)(end - beg), 1.f);
  float* pr = pooled + (size_t)g * DH + lane * 4;
  pr[0] = acc.x / cnt; pr[1] = acc.y / cnt; pr[2] = acc.z / cnt; pr[3] = acc.w / cnt;
}

__global__ void k_out(const float* __restrict__ z2, const float* __restrict__ W3,
                      const float* __restrict__ b3, float* __restrict__ out) {
  int g = blockIdx.x * 4 + (threadIdx.x >> 6);
  if (g >= NG) return;
  int lane = threadIdx.x & 63;
  float s = 0.f;
  const float* zr = z2 + (size_t)g * DM2;
  for (int k = lane; k < DM2; k += 64) s += zr[k] * W3[k];
  for (int off = 32; off > 0; off >>= 1) s += __shfl_down(s, off);
  if (lane == 0) out[g] = s + b3[0];
}

// ---------------- launcher ----------------
extern "C" void kernel_launch(void* const* d_in, const int* in_sizes, int n_in,
                              void* d_out, int out_size, void* d_ws, size_t ws_size,
                              hipStream_t stream) {
  (void)in_sizes; (void)n_in; (void)out_size; (void)ws_size;
  const float* h     = (const float*)d_in[0];
  const int*   src   = (const int*)d_in[1];
  const int*   dst   = (const int*)d_in[2];
  const int*   gid   = (const int*)d_in[3];
  const float* W_in  = (const float*)d_in[4];
  const float* b_in  = (const float*)d_in[5];
  const float* W_gcr = (const float*)d_in[6];
  const float* b_gcr = (const float*)d_in[7];
  const float* W1    = (const float*)d_in[8];
  const float* b1    = (const float*)d_in[9];
  const float* W2    = (const float*)d_in[10];
  const float* b2    = (const float*)d_in[11];
  const float* W3    = (const float*)d_in[12];
  const float* b3    = (const float*)d_in[13];
  float* out = (float*)d_out;

  char* p = (char*)d_ws;
  auto alloc = [&](size_t bytes) {
    char* q = p;
    p += (bytes + 255) & ~(size_t)255;
    return q;
  };
  int*   outdeg = (int*)alloc((size_t)NN * 4);
  int*   indeg  = (int*)alloc((size_t)NN * 4);
  float* onorm  = (float*)alloc((size_t)NN * 4);
  float* inorm  = (float*)alloc((size_t)NN * 4);
  int*   incl   = (int*)alloc((size_t)NN * 4);
  int*   bsum   = (int*)alloc(128 * 4);
  int*   offs   = (int*)alloc((size_t)(NN + 1) * 4);
  int*   cursor = (int*)alloc((size_t)NN * 4);
  int*   ssrc   = (int*)alloc((size_t)NE * 4);
  int*   gstart = (int*)alloc((size_t)(NG + 1) * 4);
  float* xbuf   = (float*)alloc((size_t)NN * DH * 4);
  float* mbuf   = (float*)alloc((size_t)NN * DH * 4);
  float* pooled = (float*)alloc((size_t)NG * DH * 4);
  float* z1     = (float*)alloc((size_t)NG * DM1 * 4);
  float* z2     = (float*)alloc((size_t)NG * DM2 * 4);

  hipMemsetAsync(outdeg, 0, (size_t)NN * 4, stream);
  hipMemsetAsync(indeg, 0, (size_t)NN * 4, stream);
  k_deg<<<(NE + 255) / 256, 256, 0, stream>>>(src, dst, outdeg, indeg);
  k_norm<<<(NN + 255) / 256, 256, 0, stream>>>(outdeg, indeg, onorm, inorm);
  int nb = (NN + 1023) / 1024;
  k_scan_block<<<nb, 1024, 0, stream>>>(indeg, incl, bsum, NN);
  k_scan_sums<<<1, 1, 0, stream>>>(bsum, nb);
  k_scan_add<<<(NN + 255) / 256, 256, 0, stream>>>(incl, bsum, indeg, offs, cursor, NN);
  k_scatter<<<(NE + 255) / 256, 256, 0, stream>>>(src, dst, cursor, ssrc);

  // input conv: aggregate in 74-dim, then GEMM 74->256 (no activation)
  k_spmm74<<<(NN + 3) / 4, 256, 0, stream>>>(h, offs, ssrc, onorm, inorm, mbuf);
  dim3 g0((NN + 63) / 64, DH / 64);
  k_gemm<0><<<g0, 256, 0, stream>>>(mbuf, W_in, b_in, xbuf, NN, DIN, DH);

  // 5 GCR blocks x 2 convs; every conv GEMM output is relu'd before next use
  for (int li = 0; li < 10; ++li) {
    k_spmm256<<<(NN + 3) / 4, 256, 0, stream>>>(xbuf, offs, ssrc, onorm, inorm, mbuf);
    k_gemm<1><<<g0, 256, 0, stream>>>(mbuf, W_gcr + (size_t)li * DH * DH, b_gcr + li * DH,
                                      xbuf, NN, DH, DH);
  }

  k_gbounds<<<(NG + 1 + 255) / 256, 256, 0, stream>>>(gid, gstart);
  k_pool<<<(NG + 3) / 4, 256, 0, stream>>>(xbuf, gstart, pooled);
  dim3 g1((NG + 63) / 64, DM1 / 64);
  k_gemm<2><<<g1, 256, 0, stream>>>(pooled, W1, b1, z1, NG, DH, DM1);
  dim3 g2((NG + 63) / 64, DM2 / 64);
  k_gemm<2><<<g2, 256, 0, stream>>>(z1, W2, b2, z2, NG, DM1, DM2);
  k_out<<<(NG + 3) / 4, 256, 0, stream>>>(z2, W3, b3, out);
}

// Round 2
// 2583.766 us; speedup vs baseline: 1.8362x; 1.8362x over previous
//
#include <hip/hip_runtime.h>
#include <hip/hip_bf16.h>

#define NN 100000
#define NE 800000
#define NG 2048
#define DIN 74
#define KPAD 96
#define DH 256
#define DM1 1024
#define DM2 512

typedef __attribute__((ext_vector_type(8))) short short8;
typedef __attribute__((ext_vector_type(4))) float f32x4;

__device__ inline ushort f2bf(float f) {
  unsigned u = __float_as_uint(f);
  unsigned r = (u + 0x7fffu + ((u >> 16) & 1u)) >> 16;
  return (ushort)r;
}
__device__ inline float bf2f(ushort h) { return __uint_as_float(((unsigned)h) << 16); }

// ---------------- degrees & norms ----------------
__global__ void k_deg(const int* __restrict__ src, const int* __restrict__ dst,
                      int* __restrict__ outd, int* __restrict__ ind) {
  int e = blockIdx.x * blockDim.x + threadIdx.x;
  if (e < NE) {
    atomicAdd(&outd[src[e]], 1);
    atomicAdd(&ind[dst[e]], 1);
  }
}

__global__ void k_norm(const int* __restrict__ outd, const int* __restrict__ ind,
                       float* __restrict__ onorm, float* __restrict__ inorm) {
  int i = blockIdx.x * blockDim.x + threadIdx.x;
  if (i < NN) {
    onorm[i] = rsqrtf(fmaxf((float)outd[i], 1.f));
    inorm[i] = rsqrtf(fmaxf((float)ind[i], 1.f));
  }
}

// ---------------- CSR build (scan + counting sort) ----------------
__global__ void k_scan_block(const int* __restrict__ deg, int* __restrict__ incl,
                             int* __restrict__ bsum, int n) {
  __shared__ int s[1024];
  int t = threadIdx.x;
  int i = blockIdx.x * 1024 + t;
  int v = (i < n) ? deg[i] : 0;
  s[t] = v;
  __syncthreads();
  for (int off = 1; off < 1024; off <<= 1) {
    int x = (t >= off) ? s[t - off] : 0;
    __syncthreads();
    s[t] += x;
    __syncthreads();
  }
  if (i < n) incl[i] = s[t];
  if (t == 1023) bsum[blockIdx.x] = s[1023];
}

__global__ void k_scan_sums(int* bsum, int nb) {
  if (threadIdx.x == 0 && blockIdx.x == 0) {
    int run = 0;
    for (int b = 0; b < nb; ++b) { int v = bsum[b]; bsum[b] = run; run += v; }
  }
}

__global__ void k_scan_add(const int* __restrict__ incl, const int* __restrict__ bsum,
                           const int* __restrict__ deg,
                           int* __restrict__ offs, int* __restrict__ cursor, int n) {
  int i = blockIdx.x * blockDim.x + threadIdx.x;
  if (i < n) {
    int v = incl[i] + bsum[i >> 10];
    offs[i + 1] = v;
    cursor[i] = v - deg[i];
    if (i == 0) offs[0] = 0;
  }
}

__global__ void k_scatter(const int* __restrict__ src, const int* __restrict__ dst,
                          int* __restrict__ cursor, int* __restrict__ ssrc) {
  int e = blockIdx.x * blockDim.x + threadIdx.x;
  if (e < NE) {
    int pos = atomicAdd(&cursor[dst[e]], 1);
    ssrc[pos] = src[e];
  }
}

// ---------------- weight convert: fp32 [k][n] -> bf16 hi/lo [n][k] ----------------
__global__ void k_convw(const float* __restrict__ W_in, const float* __restrict__ W_gcr,
                        ushort* __restrict__ Wt0h, ushort* __restrict__ Wt0l,
                        ushort* __restrict__ Wtgh, ushort* __restrict__ Wtgl) {
  int idx = blockIdx.x * blockDim.x + threadIdx.x;
  const int n0 = 256 * KPAD;
  if (idx < n0) {
    int n = idx / KPAD, k = idx - n * KPAD;
    float v = (k < DIN) ? W_in[k * 256 + n] : 0.f;
    ushort hv = f2bf(v);
    Wt0h[n * KPAD + k] = hv;
    Wt0l[n * KPAD + k] = f2bf(v - bf2f(hv));
  } else if (idx < n0 + 10 * 65536) {
    int j = idx - n0;
    int l = j >> 16, r = j & 65535;
    int n = r >> 8, k = r & 255;
    float v = W_gcr[l * 65536 + k * 256 + n];
    ushort hv = f2bf(v);
    Wtgh[l * 65536 + n * 256 + k] = hv;
    Wtgl[l * 65536 + n * 256 + k] = f2bf(v - bf2f(hv));
  }
}

// ---------------- SpMM (gather by dst row, wave per row), bf16 hi/lo output ----------------
__global__ void k_spmm74(const float* __restrict__ h, const int* __restrict__ offs,
                         const int* __restrict__ ssrc, const float* __restrict__ onorm,
                         const float* __restrict__ inorm,
                         ushort* __restrict__ Ahi, ushort* __restrict__ Alo) {
  int row = blockIdx.x * 4 + (threadIdx.x >> 6);
  if (row >= NN) return;
  int lane = threadIdx.x & 63;
  int beg = offs[row], end = offs[row + 1];
  float a0 = 0.f, a1 = 0.f;
  for (int e = beg; e < end; ++e) {
    int s = ssrc[e];
    float w = onorm[s];
    const float* hr = h + (size_t)s * DIN;
    a0 += w * hr[lane];
    if (lane < DIN - 64) a1 += w * hr[64 + lane];
  }
  float win = inorm[row];
  ushort* ph = Ahi + (size_t)row * KPAD;
  ushort* pl = Alo + (size_t)row * KPAD;
  float v0 = a0 * win;
  ushort h0 = f2bf(v0);
  ph[lane] = h0;
  pl[lane] = f2bf(v0 - bf2f(h0));
  if (lane < DIN - 64) {
    float v1 = a1 * win;
    ushort h1 = f2bf(v1);
    ph[64 + lane] = h1;
    pl[64 + lane] = f2bf(v1 - bf2f(h1));
  } else if (lane < KPAD - 64) {
    ph[64 + lane] = 0;
    pl[64 + lane] = 0;
  }
}

__global__ void k_spmm256(const float* __restrict__ x, const int* __restrict__ offs,
                          const int* __restrict__ ssrc, const float* __restrict__ onorm,
                          const float* __restrict__ inorm,
                          ushort* __restrict__ Ahi, ushort* __restrict__ Alo) {
  int row = blockIdx.x * 4 + (threadIdx.x >> 6);
  if (row >= NN) return;
  int lane = threadIdx.x & 63;
  int beg = offs[row], end = offs[row + 1];
  float4 acc = make_float4(0.f, 0.f, 0.f, 0.f);
  for (int e = beg; e < end; ++e) {
    int s = ssrc[e];
    float w = onorm[s];
    float4 v = *(const float4*)(x + (size_t)s * DH + lane * 4);
    acc.x += w * v.x; acc.y += w * v.y; acc.z += w * v.z; acc.w += w * v.w;
  }
  float win = inorm[row];
  float o[4] = {acc.x * win, acc.y * win, acc.z * win, acc.w * win};
  ushort4 hv, lv;
  hv.x = f2bf(o[0]); lv.x = f2bf(o[0] - bf2f(hv.x));
  hv.y = f2bf(o[1]); lv.y = f2bf(o[1] - bf2f(hv.y));
  hv.z = f2bf(o[2]); lv.z = f2bf(o[2] - bf2f(hv.z));
  hv.w = f2bf(o[3]); lv.w = f2bf(o[3] - bf2f(hv.w));
  *(ushort4*)(Ahi + (size_t)row * DH + lane * 4) = hv;
  *(ushort4*)(Alo + (size_t)row * DH + lane * 4) = lv;
}

// ---------------- MFMA bf16x3-split GEMM: C = A(hi+lo) @ B(hi+lo)^T_layout + bias ----------------
// A: [M][K] bf16 hi/lo row-major. B: [N][K] bf16 hi/lo (k-contiguous). ACT: 0=none, 1=relu
template <int ACT>
__global__ __launch_bounds__(256) void k_mfma(const ushort* __restrict__ Ahi,
                                              const ushort* __restrict__ Alo,
                                              const ushort* __restrict__ Bhi,
                                              const ushort* __restrict__ Blo,
                                              const float* __restrict__ bias,
                                              float* __restrict__ C,
                                              int M, int K, int Nc) {
  __shared__ ushort Ash[128 * 40], Asl[128 * 40], Bsh[128 * 40], Bsl[128 * 40];
  const int tid = threadIdx.x;
  const int lane = tid & 63;
  const int wv = tid >> 6;
  const int wm = (wv >> 1) * 64, wn = (wv & 1) * 64;
  const int quad = lane >> 4, l15 = lane & 15;
  const int r0 = blockIdx.x * 128, c0 = blockIdx.y * 128;
  f32x4 acc[4][4] = {};
  for (int k0 = 0; k0 < K; k0 += 32) {
    __syncthreads();
#pragma unroll
    for (int i = 0; i < 2; ++i) {
      int c = tid + i * 256;
      int row = c >> 2, ko = (c & 3) << 3;
      uint4 vh = {0, 0, 0, 0}, vl = {0, 0, 0, 0};
      int gr = r0 + row;
      if (gr < M) {
        vh = *(const uint4*)(Ahi + (size_t)gr * K + k0 + ko);
        vl = *(const uint4*)(Alo + (size_t)gr * K + k0 + ko);
      }
      *(uint4*)&Ash[row * 40 + ko] = vh;
      *(uint4*)&Asl[row * 40 + ko] = vl;
      int gn = c0 + row;
      *(uint4*)&Bsh[row * 40 + ko] = *(const uint4*)(Bhi + (size_t)gn * K + k0 + ko);
      *(uint4*)&Bsl[row * 40 + ko] = *(const uint4*)(Blo + (size_t)gn * K + k0 + ko);
    }
    __syncthreads();
    short8 ah[4], al[4], bh[4], bl[4];
#pragma unroll
    for (int t = 0; t < 4; ++t) {
      int ar = wm + t * 16 + l15;
      ah[t] = *(const short8*)&Ash[ar * 40 + quad * 8];
      al[t] = *(const short8*)&Asl[ar * 40 + quad * 8];
      int br = wn + t * 16 + l15;
      bh[t] = *(const short8*)&Bsh[br * 40 + quad * 8];
      bl[t] = *(const short8*)&Bsl[br * 40 + quad * 8];
    }
#pragma unroll
    for (int mt = 0; mt < 4; ++mt)
#pragma unroll
      for (int nt = 0; nt < 4; ++nt) {
        acc[mt][nt] = __builtin_amdgcn_mfma_f32_16x16x32_bf16(ah[mt], bh[nt], acc[mt][nt], 0, 0, 0);
        acc[mt][nt] = __builtin_amdgcn_mfma_f32_16x16x32_bf16(ah[mt], bl[nt], acc[mt][nt], 0, 0, 0);
        acc[mt][nt] = __builtin_amdgcn_mfma_f32_16x16x32_bf16(al[mt], bh[nt], acc[mt][nt], 0, 0, 0);
      }
  }
#pragma unroll
  for (int mt = 0; mt < 4; ++mt) {
#pragma unroll
    for (int r = 0; r < 4; ++r) {
      int gr = r0 + wm + mt * 16 + quad * 4 + r;
      if (gr >= M) continue;
#pragma unroll
      for (int nt = 0; nt < 4; ++nt) {
        int gc = c0 + wn + nt * 16 + l15;
        float v = acc[mt][nt][r] + bias[gc];
        if (ACT == 1) v = fmaxf(v, 0.f);
        C[(size_t)gr * Nc + gc] = v;
      }
    }
  }
}

// ---------------- fp32 tiled GEMM (MLP tail), fused bias + activation ----------------
template <int ACT>
__global__ __launch_bounds__(256) void k_gemm(const float* __restrict__ A,
                                              const float* __restrict__ B,
                                              const float* __restrict__ bias,
                                              float* __restrict__ C,
                                              int M, int K, int Nc) {
  __shared__ float As[16][68];
  __shared__ float Bs[16][68];
  int tid = threadIdx.x;
  int tx = tid & 15, ty = tid >> 4;
  int r0 = blockIdx.x * 64;
  int c0 = blockIdx.y * 64;
  float acc[4][4] = {};
  for (int k0 = 0; k0 < K; k0 += 16) {
#pragma unroll
    for (int idx = tid; idx < 1024; idx += 256) {
      int mm = idx >> 4, kk = idx & 15;
      int gr = r0 + mm, gk = k0 + kk;
      As[kk][mm] = (gr < M && gk < K) ? A[(size_t)gr * K + gk] : 0.f;
    }
#pragma unroll
    for (int idx = tid; idx < 1024; idx += 256) {
      int kk = idx >> 6, nn = idx & 63;
      int gk = k0 + kk, gc = c0 + nn;
      Bs[kk][nn] = (gk < K && gc < Nc) ? B[(size_t)gk * Nc + gc] : 0.f;
    }
    __syncthreads();
#pragma unroll
    for (int kk = 0; kk < 16; ++kk) {
      float4 a = *(const float4*)&As[kk][ty * 4];
      float4 b = *(const float4*)&Bs[kk][tx * 4];
      float av[4] = {a.x, a.y, a.z, a.w};
      float bv[4] = {b.x, b.y, b.z, b.w};
#pragma unroll
      for (int i = 0; i < 4; ++i)
#pragma unroll
        for (int j = 0; j < 4; ++j) acc[i][j] += av[i] * bv[j];
    }
    __syncthreads();
  }
#pragma unroll
  for (int i = 0; i < 4; ++i) {
    int gr = r0 + ty * 4 + i;
    if (gr >= M) continue;
#pragma unroll
    for (int j = 0; j < 4; ++j) {
      int gc = c0 + tx * 4 + j;
      if (gc >= Nc) continue;
      float v = acc[i][j] + bias[gc];
      if (ACT == 1) v = fmaxf(v, 0.f);
      if (ACT == 2) v = (v > 0.f) ? v : 0.01f * v;
      C[(size_t)gr * Nc + gc] = v;
    }
  }
}

// ---------------- pooling + MLP tail ----------------
__global__ void k_gbounds(const int* __restrict__ gid, int* __restrict__ gstart) {
  int g = blockIdx.x * blockDim.x + threadIdx.x;
  if (g > NG) return;
  int lo = 0, hi = NN;
  while (lo < hi) {
    int mid = (lo + hi) >> 1;
    if (gid[mid] < g) lo = mid + 1; else hi = mid;
  }
  gstart[g] = lo;
}

__global__ void k_pool(const float* __restrict__ x, const int* __restrict__ gstart,
                       float* __restrict__ pooled) {
  int g = blockIdx.x * 4 + (threadIdx.x >> 6);
  if (g >= NG) return;
  int lane = threadIdx.x & 63;
  int beg = gstart[g], end = gstart[g + 1];
  float4 acc = make_float4(0.f, 0.f, 0.f, 0.f);
  for (int r = beg; r < end; ++r) {
    float4 v = *(const float4*)(x + (size_t)r * DH + lane * 4);
    acc.x += v.x; acc.y += v.y; acc.z += v.z; acc.w += v.w;
  }
  float cnt = fmaxf((float)(end - beg), 1.f);
  float* pr = pooled + (size_t)g * DH + lane * 4;
  pr[0] = acc.x / cnt; pr[1] = acc.y / cnt; pr[2] = acc.z / cnt; pr[3] = acc.w / cnt;
}

__global__ void k_out(const float* __restrict__ z2, const float* __restrict__ W3,
                      const float* __restrict__ b3, float* __restrict__ out) {
  int g = blockIdx.x * 4 + (threadIdx.x >> 6);
  if (g >= NG) return;
  int lane = threadIdx.x & 63;
  float s = 0.f;
  const float* zr = z2 + (size_t)g * DM2;
  for (int k = lane; k < DM2; k += 64) s += zr[k] * W3[k];
  for (int off = 32; off > 0; off >>= 1) s += __shfl_down(s, off);
  if (lane == 0) out[g] = s + b3[0];
}

// ---------------- launcher ----------------
extern "C" void kernel_launch(void* const* d_in, const int* in_sizes, int n_in,
                              void* d_out, int out_size, void* d_ws, size_t ws_size,
                              hipStream_t stream) {
  (void)in_sizes; (void)n_in; (void)out_size; (void)ws_size;
  const float* h     = (const float*)d_in[0];
  const int*   src   = (const int*)d_in[1];
  const int*   dst   = (const int*)d_in[2];
  const int*   gid   = (const int*)d_in[3];
  const float* W_in  = (const float*)d_in[4];
  const float* b_in  = (const float*)d_in[5];
  const float* W_gcr = (const float*)d_in[6];
  const float* b_gcr = (const float*)d_in[7];
  const float* W1    = (const float*)d_in[8];
  const float* b1    = (const float*)d_in[9];
  const float* W2    = (const float*)d_in[10];
  const float* b2    = (const float*)d_in[11];
  const float* W3    = (const float*)d_in[12];
  const float* b3    = (const float*)d_in[13];
  float* out = (float*)d_out;

  char* p = (char*)d_ws;
  auto alloc = [&](size_t bytes) {
    char* q = p;
    p += (bytes + 255) & ~(size_t)255;
    return q;
  };
  int*    outdeg = (int*)alloc((size_t)NN * 4);
  int*    indeg  = (int*)alloc((size_t)NN * 4);
  float*  onorm  = (float*)alloc((size_t)NN * 4);
  float*  inorm  = (float*)alloc((size_t)NN * 4);
  int*    incl   = (int*)alloc((size_t)NN * 4);
  int*    bsum   = (int*)alloc(128 * 4);
  int*    offs   = (int*)alloc((size_t)(NN + 1) * 4);
  int*    cursor = (int*)alloc((size_t)NN * 4);
  int*    ssrc   = (int*)alloc((size_t)NE * 4);
  int*    gstart = (int*)alloc((size_t)(NG + 1) * 4);
  float*  xbuf   = (float*)alloc((size_t)NN * DH * 4);
  ushort* Ahi    = (ushort*)alloc((size_t)NN * DH * 2);
  ushort* Alo    = (ushort*)alloc((size_t)NN * DH * 2);
  ushort* Wt0h   = (ushort*)alloc((size_t)256 * KPAD * 2);
  ushort* Wt0l   = (ushort*)alloc((size_t)256 * KPAD * 2);
  ushort* Wtgh   = (ushort*)alloc((size_t)10 * 256 * 256 * 2);
  ushort* Wtgl   = (ushort*)alloc((size_t)10 * 256 * 256 * 2);
  float*  pooled = (float*)alloc((size_t)NG * DH * 4);
  float*  z1     = (float*)alloc((size_t)NG * DM1 * 4);
  float*  z2     = (float*)alloc((size_t)NG * DM2 * 4);

  hipMemsetAsync(outdeg, 0, (size_t)NN * 4, stream);
  hipMemsetAsync(indeg, 0, (size_t)NN * 4, stream);
  k_deg<<<(NE + 255) / 256, 256, 0, stream>>>(src, dst, outdeg, indeg);
  k_norm<<<(NN + 255) / 256, 256, 0, stream>>>(outdeg, indeg, onorm, inorm);
  int nb = (NN + 1023) / 1024;
  k_scan_block<<<nb, 1024, 0, stream>>>(indeg, incl, bsum, NN);
  k_scan_sums<<<1, 1, 0, stream>>>(bsum, nb);
  k_scan_add<<<(NN + 255) / 256, 256, 0, stream>>>(incl, bsum, indeg, offs, cursor, NN);
  k_scatter<<<(NE + 255) / 256, 256, 0, stream>>>(src, dst, cursor, ssrc);

  int nconv = 256 * KPAD + 10 * 65536;
  k_convw<<<(nconv + 255) / 256, 256, 0, stream>>>(W_in, W_gcr, Wt0h, Wt0l, Wtgh, Wtgl);

  dim3 gmm((NN + 127) / 128, DH / 128);

  // input conv: aggregate 74-dim (pad to 96), MFMA GEMM 96->256, no activation
  k_spmm74<<<(NN + 3) / 4, 256, 0, stream>>>(h, offs, ssrc, onorm, inorm, Ahi, Alo);
  k_mfma<0><<<gmm, 256, 0, stream>>>(Ahi, Alo, Wt0h, Wt0l, b_in, xbuf, NN, KPAD, DH);

  // 5 GCR blocks x 2 convs; every conv GEMM output is relu'd before next use
  for (int li = 0; li < 10; ++li) {
    k_spmm256<<<(NN + 3) / 4, 256, 0, stream>>>(xbuf, offs, ssrc, onorm, inorm, Ahi, Alo);
    k_mfma<1><<<gmm, 256, 0, stream>>>(Ahi, Alo, Wtgh + (size_t)li * 65536,
                                       Wtgl + (size_t)li * 65536, b_gcr + li * 256,
                                       xbuf, NN, DH, DH);
  }

  k_gbounds<<<(NG + 1 + 255) / 256, 256, 0, stream>>>(gid, gstart);
  k_pool<<<(NG + 3) / 4, 256, 0, stream>>>(xbuf, gstart, pooled);
  dim3 g1((NG + 63) / 64, DM1 / 64);
  k_gemm<2><<<g1, 256, 0, stream>>>(pooled, W1, b1, z1, NG, DH, DM1);
  dim3 g2((NG + 63) / 64, DM2 / 64);
  k_gemm<2><<<g2, 256, 0, stream>>>(z1, W2, b2, z2, NG, DM1, DM2);
  k_out<<<(NG + 3) / 4, 256, 0, stream>>>(z2, W3, b3, out);
}